// Round 2
// baseline (748.174 us; speedup 1.0000x reference)
//
#include <hip/hip_runtime.h>

// ---------------------------------------------------------------------------
// 12-qubit state-vector sim, one sample per 64-lane wave.
// Storage index p (12 bits): bits 0..5 = per-thread local index j,
// bits 6..11 = lane id. Logical index k = M*p over GF(2); M starts as I,
// every CNOT(c->t) is absorbed as a row op on M (zero data movement).
// A 1q gate on logical bit b pairs storage p with p ^ col_b(M^-1) and the
// "which side" bit is parity(p & row_b(M)). All masks are constexpr.
// Bit convention: wire w  <->  bit (11-w) of k   (wire 0 = MSB, PennyLane).
//
// Invariant: parity(pair & side) == 1 over the full 12 bits. The LOCAL
// parity parity(pml & sml) may be 0 or 1 in the mixed (cross-lane) case;
// partner's local side bit is sj ^ parity(pml & sml)  (round-1 bugfix).
// ---------------------------------------------------------------------------

#define N_GATES 48

struct Circ {
    unsigned pair[N_GATES];
    unsigned side[N_GATES];
    unsigned meas[12];
};

constexpr Circ make_circ() {
    Circ c{};
    unsigned Mrow[12] = {}, Ucol[12] = {};   // M rows, M^-1 columns
    for (int i = 0; i < 12; ++i) { Mrow[i] = 1u << i; Ucol[i] = 1u << i; }
    int g = 0;
    for (int l = 0; l < 4; ++l) {
        // 12 Rot gates on wires 0..11 (before this layer's CNOTs)
        for (int w = 0; w < 12; ++w) {
            int b = 11 - w;
            c.pair[g] = Ucol[b];
            c.side[g] = Mrow[b];
            ++g;
        }
        // CNOT chain: (0,1),(1,2),...,(10,11) then (11,0); bits c=11-i, t=10-i
        for (int i = 0; i < 11; ++i) {
            int cb = 11 - i, tb = 10 - i;
            Mrow[tb] ^= Mrow[cb];
            Ucol[cb] ^= Ucol[tb];
        }
        // CNOT(11 -> 0): control bit 0, target bit 11
        Mrow[11] ^= Mrow[0];
        Ucol[0]  ^= Ucol[11];
    }
    for (int w = 0; w < 12; ++w) c.meas[w] = Mrow[11 - w];
    return c;
}

constexpr Circ CIRC = make_circ();

template <int G>
__device__ __forceinline__ void apply_gate(float (&ar)[64], float (&ai)[64],
                                           const float* __restrict__ m, int lane) {
    constexpr unsigned pm  = CIRC.pair[G];
    constexpr unsigned sm  = CIRC.side[G];
    constexpr unsigned pml = pm & 63u;
    constexpr unsigned pmh = pm >> 6;
    constexpr unsigned sml = sm & 63u;
    constexpr unsigned smh = sm >> 6;
    // partner's local side parity differs from ours iff this is 1
    constexpr bool flip = (__builtin_popcount(pml & sml) & 1) != 0;

    const float u00r = m[0], u00i = m[1], u01r = m[2], u01i = m[3];
    const float u10r = m[4], u10i = m[5], u11r = m[6], u11i = m[7];

    // runtime lane contribution to the side bit
    const int sL = __popc(lane & (int)smh) & 1;
    // own/partner coefficients for local-parity sj = 0 and sj = 1
    const float p0r = sL ? u11r : u00r, p0i = sL ? u11i : u00i;
    const float q0r = sL ? u10r : u01r, q0i = sL ? u10i : u01i;
    const float p1r = sL ? u00r : u11r, p1i = sL ? u00i : u11i;
    const float q1r = sL ? u01r : u10r, q1i = sL ? u01i : u10i;

    if constexpr (pmh == 0u) {
        // purely in-thread pairs (flip is guaranteed 1 here)
        constexpr int msb = 1 << (31 - __builtin_clz(pml));
#pragma unroll
        for (int j = 0; j < 64; ++j) {
            if ((j & msb) == 0) {
                const int j2 = j ^ (int)pml;
                const bool sj  = __builtin_parity(j & (int)sml);
                const bool sjB = flip ? !sj : sj;
                const float cAr = sj ? p1r : p0r, cAi = sj ? p1i : p0i;
                const float dAr = sj ? q1r : q0r, dAi = sj ? q1i : q0i;
                const float cBr = sjB ? p1r : p0r, cBi = sjB ? p1i : p0i;
                const float dBr = sjB ? q1r : q0r, dBi = sjB ? q1i : q0i;
                const float Arr = ar[j],  Aii = ai[j];
                const float Brr = ar[j2], Bii = ai[j2];
                ar[j]  = cAr * Arr - cAi * Aii + dAr * Brr - dAi * Bii;
                ai[j]  = cAr * Aii + cAi * Arr + dAr * Bii + dAi * Brr;
                ar[j2] = cBr * Brr - cBi * Bii + dBr * Arr - dBi * Aii;
                ai[j2] = cBr * Bii + cBi * Brr + dBr * Aii + dBi * Arr;
            }
        }
    } else if constexpr (pml == 0u) {
        // pure cross-lane pairs: partner is same j in lane ^ pmh
#pragma unroll
        for (int j = 0; j < 64; ++j) {
            const bool sj = __builtin_parity(j & (int)sml);
            const float cr = sj ? p1r : p0r, ci = sj ? p1i : p0i;
            const float dr = sj ? q1r : q0r, di = sj ? q1i : q0i;
            const float br = __shfl_xor(ar[j], (int)pmh, 64);
            const float bi = __shfl_xor(ai[j], (int)pmh, 64);
            const float Arr = ar[j], Aii = ai[j];
            ar[j] = cr * Arr - ci * Aii + dr * br - di * bi;
            ai[j] = cr * Aii + ci * Arr + dr * bi + di * br;
        }
    } else {
        // mixed: partner is (lane ^ pmh, j ^ pml); read both olds before writes
        constexpr int msb = 1 << (31 - __builtin_clz(pml));
#pragma unroll
        for (int j = 0; j < 64; ++j) {
            if ((j & msb) == 0) {
                const int j2 = j ^ (int)pml;
                const bool sj  = __builtin_parity(j & (int)sml);
                const bool sjB = flip ? !sj : sj;   // round-1 fix: was !sj always
                const float bAr = __shfl_xor(ar[j2], (int)pmh, 64);
                const float bAi = __shfl_xor(ai[j2], (int)pmh, 64);
                const float bBr = __shfl_xor(ar[j],  (int)pmh, 64);
                const float bBi = __shfl_xor(ai[j],  (int)pmh, 64);
                const float cAr = sj ? p1r : p0r, cAi = sj ? p1i : p0i;
                const float dAr = sj ? q1r : q0r, dAi = sj ? q1i : q0i;
                const float cBr = sjB ? p1r : p0r, cBi = sjB ? p1i : p0i;
                const float dBr = sjB ? q1r : q0r, dBi = sjB ? q1i : q0i;
                const float Arr = ar[j],  Aii = ai[j];
                const float Brr = ar[j2], Bii = ai[j2];
                ar[j]  = cAr * Arr - cAi * Aii + dAr * bAr - dAi * bAi;
                ai[j]  = cAr * Aii + cAi * Arr + dAr * bAi + dAi * bAr;
                ar[j2] = cBr * Brr - cBi * Bii + dBr * bBr - dBi * bBi;
                ai[j2] = cBr * Bii + cBi * Brr + dBr * bBi + dBi * bBr;
            }
        }
    }
}

template <int G>
__device__ __forceinline__ void apply_from(float (&ar)[64], float (&ai)[64],
                                           const float (*rotm)[8], int lane) {
    if constexpr (G < N_GATES) {
        apply_gate<G>(ar, ai, rotm[G], lane);
        apply_from<G + 1>(ar, ai, rotm, lane);
    }
}

__global__ __launch_bounds__(64)
void qsim_kernel(const float* __restrict__ inputs,
                 const float* __restrict__ theta,
                 float* __restrict__ out) {
    __shared__ float rotm[N_GATES][8];
    const int lane = threadIdx.x;
    const int b = blockIdx.x;

    // ---- 48 shared Rot matrices (lanes 0..47), PennyLane Rot(phi,th,om) ----
    if (lane < N_GATES) {
        const float* th = theta + lane * 3;   // lane = l*12 + w = gate index
        const float phi = th[0], tht = th[1], om = th[2];
        const float ct = __cosf(0.5f * tht), st = __sinf(0.5f * tht);
        const float a = 0.5f * (phi + om), d = 0.5f * (phi - om);
        const float ca = __cosf(a), sa = __sinf(a);
        const float cd = __cosf(d), sd = __sinf(d);
        rotm[lane][0] = ca * ct;  rotm[lane][1] = -sa * ct;   // u00 = e^{-ia} ct
        rotm[lane][2] = -cd * st; rotm[lane][3] = -sd * st;   // u01 = -e^{+id} st
        rotm[lane][4] = cd * st;  rotm[lane][5] = -sd * st;   // u10 = e^{-id} st
        rotm[lane][6] = ca * ct;  rotm[lane][7] = sa * ct;    // u11 = e^{+ia} ct
    }
    __syncthreads();

    // ---- init: RY-encoded product state (real) ----
    float cw[12], sw[12];
    const float* xin = inputs + b * 12;
#pragma unroll
    for (int w = 0; w < 12; ++w) {
        const float h = 0.5f * xin[w];
        cw[w] = __cosf(h);
        sw[w] = __sinf(h);
    }
    // lane bits: p bit (lb+6) <-> wire (5-lb)  =>  wire w (0..5) = lane bit (5-w)
    float prodL = 1.0f;
#pragma unroll
    for (int w = 0; w < 6; ++w)
        prodL *= ((lane >> (5 - w)) & 1) ? sw[w] : cw[w];

    float ar[64], ai[64];
    ar[0] = prodL;
#pragma unroll
    for (int k = 0; k < 6; ++k) {            // local bit k <-> wire (11-k)
        const int n = 1 << k;
#pragma unroll
        for (int idx = 0; idx < n; ++idx) {
            const float v = ar[idx];
            ar[idx + n] = v * sw[11 - k];
            ar[idx]     = v * cw[11 - k];
        }
    }
#pragma unroll
    for (int j = 0; j < 64; ++j) ai[j] = 0.0f;

    // ---- 4 layers x 12 Rot gates (CNOTs folded into masks) ----
    apply_from<0>(ar, ai, rotm, lane);

    // ---- measurement: <Z_q> = sum_p |amp|^2 * (1-2*parity(p & meas[q])) ----
    float sums[12];
#pragma unroll
    for (int q = 0; q < 12; ++q) sums[q] = 0.0f;
#pragma unroll
    for (int j = 0; j < 64; ++j) {
        const float p = ar[j] * ar[j] + ai[j] * ai[j];
#pragma unroll
        for (int q = 0; q < 12; ++q) {
            if (__builtin_parity(j & (int)(CIRC.meas[q] & 63u)))
                sums[q] -= p;
            else
                sums[q] += p;
        }
    }
#pragma unroll
    for (int q = 0; q < 12; ++q) {
        float v = (__popc(lane & (int)(CIRC.meas[q] >> 6)) & 1) ? -sums[q] : sums[q];
        v += __shfl_xor(v, 32, 64);
        v += __shfl_xor(v, 16, 64);
        v += __shfl_xor(v, 8, 64);
        v += __shfl_xor(v, 4, 64);
        v += __shfl_xor(v, 2, 64);
        v += __shfl_xor(v, 1, 64);
        if (lane == 0) out[b * 12 + q] = v;
    }
}

extern "C" void kernel_launch(void* const* d_in, const int* in_sizes, int n_in,
                              void* d_out, int out_size, void* d_ws, size_t ws_size,
                              hipStream_t stream) {
    const float* inputs = (const float*)d_in[0];
    const float* theta  = (const float*)d_in[1];
    float* out = (float*)d_out;
    const int B = in_sizes[0] / 12;
    qsim_kernel<<<B, 64, 0, stream>>>(inputs, theta, out);
}

// Round 3
// 418.758 us; speedup vs baseline: 1.7867x; 1.7867x over previous
//
#include <hip/hip_runtime.h>

// ---------------------------------------------------------------------------
// 12-qubit state-vector sim, one sample per 64-lane wave, 4 samples/block.
// Storage index p (12 bits): bits 0..5 = per-thread local index j,
// bits 6..11 = lane id. Logical index k = M*p over GF(2); M starts as I,
// every CNOT(c->t) is absorbed as a row op on M (zero data movement).
// A 1q gate on logical bit b pairs storage p with p ^ col_b(M^-1) and the
// "which side" bit is parity(p & row_b(M)). All masks are constexpr.
// Bit convention: wire w  <->  bit (11-w) of k   (wire 0 = MSB, PennyLane).
//
// Invariant: parity(pair & side) == 1 over the full 12 bits; partner's local
// side bit is sj ^ parity(pml & sml).
//
// Round-3 changes (same math as the passing round-2 kernel):
//  - 256-thread blocks (4 waves = 4 samples) to lift the workgroup-slot
//    occupancy cap (was 12%).
//  - shuffle results batched 16-at-a-time into static temp arrays so the
//    DS pipe has MLP instead of issue->waitcnt->use serialization.
//  - __launch_bounds__(256,3) caps VGPR at ~170 (3 waves/SIMD).
// ---------------------------------------------------------------------------

#define N_GATES 48

struct Circ {
    unsigned pair[N_GATES];
    unsigned side[N_GATES];
    unsigned meas[12];
};

constexpr Circ make_circ() {
    Circ c{};
    unsigned Mrow[12] = {}, Ucol[12] = {};   // M rows, M^-1 columns
    for (int i = 0; i < 12; ++i) { Mrow[i] = 1u << i; Ucol[i] = 1u << i; }
    int g = 0;
    for (int l = 0; l < 4; ++l) {
        for (int w = 0; w < 12; ++w) {
            int b = 11 - w;
            c.pair[g] = Ucol[b];
            c.side[g] = Mrow[b];
            ++g;
        }
        // CNOT chain: (0,1),(1,2),...,(10,11) then (11,0); bits c=11-i, t=10-i
        for (int i = 0; i < 11; ++i) {
            int cb = 11 - i, tb = 10 - i;
            Mrow[tb] ^= Mrow[cb];
            Ucol[cb] ^= Ucol[tb];
        }
        Mrow[11] ^= Mrow[0];   // CNOT(11 -> 0): control bit 0, target bit 11
        Ucol[0]  ^= Ucol[11];
    }
    for (int w = 0; w < 12; ++w) c.meas[w] = Mrow[11 - w];
    return c;
}

constexpr Circ CIRC = make_circ();

// c-th pair slot for in-thread/mixed gates: insert a 0 bit at position MSB
__device__ __forceinline__ constexpr int pidx(int c, int msb) {
    return ((c & ~(msb - 1)) << 1) | (c & (msb - 1));
}

template <int G>
__device__ __forceinline__ void apply_gate(float (&ar)[64], float (&ai)[64],
                                           const float* __restrict__ m, int lane) {
    constexpr unsigned pm  = CIRC.pair[G];
    constexpr unsigned sm  = CIRC.side[G];
    constexpr unsigned pml = pm & 63u;
    constexpr unsigned pmh = pm >> 6;
    constexpr unsigned sml = sm & 63u;
    constexpr unsigned smh = sm >> 6;
    // partner's local side parity differs from ours iff this is 1
    constexpr bool flip = (__builtin_popcount(pml & sml) & 1) != 0;

    const float u00r = m[0], u00i = m[1], u01r = m[2], u01i = m[3];
    const float u10r = m[4], u10i = m[5], u11r = m[6], u11i = m[7];

    // runtime lane contribution to the side bit
    const int sL = __popc(lane & (int)smh) & 1;
    // own/partner coefficients for local-parity sj = 0 and sj = 1
    const float p0r = sL ? u11r : u00r, p0i = sL ? u11i : u00i;
    const float q0r = sL ? u10r : u01r, q0i = sL ? u10i : u01i;
    const float p1r = sL ? u00r : u11r, p1i = sL ? u00i : u11i;
    const float q1r = sL ? u01r : u10r, q1i = sL ? u01i : u10i;

    if constexpr (pmh == 0u) {
        // purely in-thread pairs (flip is guaranteed 1 here)
        constexpr int msb = 1 << (31 - __builtin_clz(pml));
#pragma unroll
        for (int c = 0; c < 32; ++c) {
            const int j  = pidx(c, msb);
            const int j2 = j ^ (int)pml;
            const bool sj  = __builtin_parity(j & (int)sml);
            const bool sjB = flip ? !sj : sj;
            const float cAr = sj ? p1r : p0r, cAi = sj ? p1i : p0i;
            const float dAr = sj ? q1r : q0r, dAi = sj ? q1i : q0i;
            const float cBr = sjB ? p1r : p0r, cBi = sjB ? p1i : p0i;
            const float dBr = sjB ? q1r : q0r, dBi = sjB ? q1i : q0i;
            const float Arr = ar[j],  Aii = ai[j];
            const float Brr = ar[j2], Bii = ai[j2];
            ar[j]  = cAr * Arr - cAi * Aii + dAr * Brr - dAi * Bii;
            ai[j]  = cAr * Aii + cAi * Arr + dAr * Bii + dAi * Brr;
            ar[j2] = cBr * Brr - cBi * Bii + dBr * Arr - dBi * Aii;
            ai[j2] = cBr * Bii + cBi * Brr + dBr * Aii + dBi * Arr;
        }
    } else if constexpr (pml == 0u) {
        // pure cross-lane pairs: partner is same j in lane ^ pmh.
        // batch 8 elements (16 shuffles) per chunk for DS-pipe MLP.
#pragma unroll
        for (int j0 = 0; j0 < 64; j0 += 8) {
            float br[8], bi[8];
#pragma unroll
            for (int k = 0; k < 8; ++k) {
                br[k] = __shfl_xor(ar[j0 + k], (int)pmh, 64);
                bi[k] = __shfl_xor(ai[j0 + k], (int)pmh, 64);
            }
#pragma unroll
            for (int k = 0; k < 8; ++k) {
                const int j = j0 + k;
                const bool sj = __builtin_parity(j & (int)sml);
                const float cr = sj ? p1r : p0r, ci = sj ? p1i : p0i;
                const float dr = sj ? q1r : q0r, di = sj ? q1i : q0i;
                const float Arr = ar[j], Aii = ai[j];
                ar[j] = cr * Arr - ci * Aii + dr * br[k] - di * bi[k];
                ai[j] = cr * Aii + ci * Arr + dr * bi[k] + di * br[k];
            }
        }
    } else {
        // mixed: partner is (lane ^ pmh, j ^ pml).
        // batch 4 pairs (16 shuffles) per chunk.
        constexpr int msb = 1 << (31 - __builtin_clz(pml));
#pragma unroll
        for (int c0 = 0; c0 < 32; c0 += 4) {
            float tAr[4], tAi[4], tBr[4], tBi[4];
#pragma unroll
            for (int k = 0; k < 4; ++k) {
                const int j  = pidx(c0 + k, msb);
                const int j2 = j ^ (int)pml;
                tAr[k] = __shfl_xor(ar[j2], (int)pmh, 64);
                tAi[k] = __shfl_xor(ai[j2], (int)pmh, 64);
                tBr[k] = __shfl_xor(ar[j],  (int)pmh, 64);
                tBi[k] = __shfl_xor(ai[j],  (int)pmh, 64);
            }
#pragma unroll
            for (int k = 0; k < 4; ++k) {
                const int j  = pidx(c0 + k, msb);
                const int j2 = j ^ (int)pml;
                const bool sj  = __builtin_parity(j & (int)sml);
                const bool sjB = flip ? !sj : sj;
                const float cAr = sj ? p1r : p0r, cAi = sj ? p1i : p0i;
                const float dAr = sj ? q1r : q0r, dAi = sj ? q1i : q0i;
                const float cBr = sjB ? p1r : p0r, cBi = sjB ? p1i : p0i;
                const float dBr = sjB ? q1r : q0r, dBi = sjB ? q1i : q0i;
                const float Arr = ar[j],  Aii = ai[j];
                const float Brr = ar[j2], Bii = ai[j2];
                ar[j]  = cAr * Arr - cAi * Aii + dAr * tAr[k] - dAi * tAi[k];
                ai[j]  = cAr * Aii + cAi * Arr + dAr * tAi[k] + dAi * tAr[k];
                ar[j2] = cBr * Brr - cBi * Bii + dBr * tBr[k] - dBi * tBi[k];
                ai[j2] = cBr * Bii + cBi * Brr + dBr * tBi[k] + dBi * tBr[k];
            }
        }
    }
}

template <int G>
__device__ __forceinline__ void apply_from(float (&ar)[64], float (&ai)[64],
                                           const float (*rotm)[8], int lane) {
    if constexpr (G < N_GATES) {
        apply_gate<G>(ar, ai, rotm[G], lane);
        apply_from<G + 1>(ar, ai, rotm, lane);
    }
}

__global__ __launch_bounds__(256, 3)
void qsim_kernel(const float* __restrict__ inputs,
                 const float* __restrict__ theta,
                 float* __restrict__ out, int B) {
    __shared__ float rotm[N_GATES][8];
    const int tid  = threadIdx.x;
    const int lane = tid & 63;
    int b = blockIdx.x * 4 + (tid >> 6);
    if (b >= B) b = B - 1;   // duplicate work, identical writes (B%4==0 normally)

    // ---- 48 shared Rot matrices (threads 0..47), PennyLane Rot(phi,th,om) ----
    if (tid < N_GATES) {
        const float* th = theta + tid * 3;   // tid = l*12 + w = gate index
        const float phi = th[0], tht = th[1], om = th[2];
        const float ct = __cosf(0.5f * tht), st = __sinf(0.5f * tht);
        const float a = 0.5f * (phi + om), d = 0.5f * (phi - om);
        const float ca = __cosf(a), sa = __sinf(a);
        const float cd = __cosf(d), sd = __sinf(d);
        rotm[tid][0] = ca * ct;  rotm[tid][1] = -sa * ct;   // u00 = e^{-ia} ct
        rotm[tid][2] = -cd * st; rotm[tid][3] = -sd * st;   // u01 = -e^{+id} st
        rotm[tid][4] = cd * st;  rotm[tid][5] = -sd * st;   // u10 = e^{-id} st
        rotm[tid][6] = ca * ct;  rotm[tid][7] = sa * ct;    // u11 = e^{+ia} ct
    }
    __syncthreads();

    // ---- init: RY-encoded product state (real) ----
    float cw[12], sw[12];
    const float* xin = inputs + b * 12;
#pragma unroll
    for (int w = 0; w < 12; ++w) {
        const float h = 0.5f * xin[w];
        cw[w] = __cosf(h);
        sw[w] = __sinf(h);
    }
    // lane bits: p bit (lb+6) <-> wire (5-lb)  =>  wire w (0..5) = lane bit (5-w)
    float prodL = 1.0f;
#pragma unroll
    for (int w = 0; w < 6; ++w)
        prodL *= ((lane >> (5 - w)) & 1) ? sw[w] : cw[w];

    float ar[64], ai[64];
    ar[0] = prodL;
#pragma unroll
    for (int k = 0; k < 6; ++k) {            // local bit k <-> wire (11-k)
        const int n = 1 << k;
#pragma unroll
        for (int idx = 0; idx < n; ++idx) {
            const float v = ar[idx];
            ar[idx + n] = v * sw[11 - k];
            ar[idx]     = v * cw[11 - k];
        }
    }
#pragma unroll
    for (int j = 0; j < 64; ++j) ai[j] = 0.0f;

    // ---- 4 layers x 12 Rot gates (CNOTs folded into masks) ----
    apply_from<0>(ar, ai, rotm, lane);

    // ---- measurement: <Z_q> = sum_p |amp|^2 * (1-2*parity(p & meas[q])) ----
    float sums[12];
#pragma unroll
    for (int q = 0; q < 12; ++q) sums[q] = 0.0f;
#pragma unroll
    for (int j = 0; j < 64; ++j) {
        const float p = ar[j] * ar[j] + ai[j] * ai[j];
#pragma unroll
        for (int q = 0; q < 12; ++q) {
            if (__builtin_parity(j & (int)(CIRC.meas[q] & 63u)))
                sums[q] -= p;
            else
                sums[q] += p;
        }
    }
#pragma unroll
    for (int q = 0; q < 12; ++q) {
        float v = (__popc(lane & (int)(CIRC.meas[q] >> 6)) & 1) ? -sums[q] : sums[q];
        v += __shfl_xor(v, 32, 64);
        v += __shfl_xor(v, 16, 64);
        v += __shfl_xor(v, 8, 64);
        v += __shfl_xor(v, 4, 64);
        v += __shfl_xor(v, 2, 64);
        v += __shfl_xor(v, 1, 64);
        if (lane == 0) out[b * 12 + q] = v;
    }
}

extern "C" void kernel_launch(void* const* d_in, const int* in_sizes, int n_in,
                              void* d_out, int out_size, void* d_ws, size_t ws_size,
                              hipStream_t stream) {
    const float* inputs = (const float*)d_in[0];
    const float* theta  = (const float*)d_in[1];
    float* out = (float*)d_out;
    const int B = in_sizes[0] / 12;
    const int blocks = (B + 3) / 4;
    qsim_kernel<<<blocks, 256, 0, stream>>>(inputs, theta, out, B);
}

// Round 4
// 407.153 us; speedup vs baseline: 1.8376x; 1.0285x over previous
//
#include <hip/hip_runtime.h>

// ---------------------------------------------------------------------------
// 12-qubit state-vector sim, one sample per 64-lane wave, 4 samples/block.
// Storage index p (12 bits): bits 0..5 = per-thread local index j,
// bits 6..11 = lane id. Logical index k = M*p over GF(2); M starts as I,
// every CNOT(c->t) is absorbed as a row op on M (zero data movement).
// A 1q gate on logical bit b pairs storage p with p ^ col_b(M^-1) and the
// "which side" bit is parity(p & row_b(M)). All masks are constexpr.
// Bit convention: wire w  <->  bit (11-w) of k   (wire 0 = MSB, PennyLane).
//
// Invariant: parity(pair & side) == 1 over the full 12 bits; partner's local
// side bit is sj ^ parity(pml & sml).
//
// Round-4 change (ONLY): __launch_bounds__(256,3) -> (256,2).
// Round 3's (256,3) capped VGPRs at ~168 < peak pressure (~190): allocator
// spilled the state to scratch (VGPR_Count=84, 290 MB HBM traffic/dispatch).
// Cap 256 keeps the 128-reg state resident; 2 waves/SIMD is enough because
// the 32 independent pairs per gate give the VALU full ILP within one wave.
// ---------------------------------------------------------------------------

#define N_GATES 48

struct Circ {
    unsigned pair[N_GATES];
    unsigned side[N_GATES];
    unsigned meas[12];
};

constexpr Circ make_circ() {
    Circ c{};
    unsigned Mrow[12] = {}, Ucol[12] = {};   // M rows, M^-1 columns
    for (int i = 0; i < 12; ++i) { Mrow[i] = 1u << i; Ucol[i] = 1u << i; }
    int g = 0;
    for (int l = 0; l < 4; ++l) {
        for (int w = 0; w < 12; ++w) {
            int b = 11 - w;
            c.pair[g] = Ucol[b];
            c.side[g] = Mrow[b];
            ++g;
        }
        // CNOT chain: (0,1),(1,2),...,(10,11) then (11,0); bits c=11-i, t=10-i
        for (int i = 0; i < 11; ++i) {
            int cb = 11 - i, tb = 10 - i;
            Mrow[tb] ^= Mrow[cb];
            Ucol[cb] ^= Ucol[tb];
        }
        Mrow[11] ^= Mrow[0];   // CNOT(11 -> 0): control bit 0, target bit 11
        Ucol[0]  ^= Ucol[11];
    }
    for (int w = 0; w < 12; ++w) c.meas[w] = Mrow[11 - w];
    return c;
}

constexpr Circ CIRC = make_circ();

// c-th pair slot for in-thread/mixed gates: insert a 0 bit at position MSB
__device__ __forceinline__ constexpr int pidx(int c, int msb) {
    return ((c & ~(msb - 1)) << 1) | (c & (msb - 1));
}

template <int G>
__device__ __forceinline__ void apply_gate(float (&ar)[64], float (&ai)[64],
                                           const float* __restrict__ m, int lane) {
    constexpr unsigned pm  = CIRC.pair[G];
    constexpr unsigned sm  = CIRC.side[G];
    constexpr unsigned pml = pm & 63u;
    constexpr unsigned pmh = pm >> 6;
    constexpr unsigned sml = sm & 63u;
    constexpr unsigned smh = sm >> 6;
    // partner's local side parity differs from ours iff this is 1
    constexpr bool flip = (__builtin_popcount(pml & sml) & 1) != 0;

    const float u00r = m[0], u00i = m[1], u01r = m[2], u01i = m[3];
    const float u10r = m[4], u10i = m[5], u11r = m[6], u11i = m[7];

    // runtime lane contribution to the side bit
    const int sL = __popc(lane & (int)smh) & 1;
    // own/partner coefficients for local-parity sj = 0 and sj = 1
    const float p0r = sL ? u11r : u00r, p0i = sL ? u11i : u00i;
    const float q0r = sL ? u10r : u01r, q0i = sL ? u10i : u01i;
    const float p1r = sL ? u00r : u11r, p1i = sL ? u00i : u11i;
    const float q1r = sL ? u01r : u10r, q1i = sL ? u01i : u10i;

    if constexpr (pmh == 0u) {
        // purely in-thread pairs (flip is guaranteed 1 here)
        constexpr int msb = 1 << (31 - __builtin_clz(pml));
#pragma unroll
        for (int c = 0; c < 32; ++c) {
            const int j  = pidx(c, msb);
            const int j2 = j ^ (int)pml;
            const bool sj  = __builtin_parity(j & (int)sml);
            const bool sjB = flip ? !sj : sj;
            const float cAr = sj ? p1r : p0r, cAi = sj ? p1i : p0i;
            const float dAr = sj ? q1r : q0r, dAi = sj ? q1i : q0i;
            const float cBr = sjB ? p1r : p0r, cBi = sjB ? p1i : p0i;
            const float dBr = sjB ? q1r : q0r, dBi = sjB ? q1i : q0i;
            const float Arr = ar[j],  Aii = ai[j];
            const float Brr = ar[j2], Bii = ai[j2];
            ar[j]  = cAr * Arr - cAi * Aii + dAr * Brr - dAi * Bii;
            ai[j]  = cAr * Aii + cAi * Arr + dAr * Bii + dAi * Brr;
            ar[j2] = cBr * Brr - cBi * Bii + dBr * Arr - dBi * Aii;
            ai[j2] = cBr * Bii + cBi * Brr + dBr * Aii + dBi * Arr;
        }
    } else if constexpr (pml == 0u) {
        // pure cross-lane pairs: partner is same j in lane ^ pmh.
        // batch 8 elements (16 shuffles) per chunk for DS-pipe MLP.
#pragma unroll
        for (int j0 = 0; j0 < 64; j0 += 8) {
            float br[8], bi[8];
#pragma unroll
            for (int k = 0; k < 8; ++k) {
                br[k] = __shfl_xor(ar[j0 + k], (int)pmh, 64);
                bi[k] = __shfl_xor(ai[j0 + k], (int)pmh, 64);
            }
#pragma unroll
            for (int k = 0; k < 8; ++k) {
                const int j = j0 + k;
                const bool sj = __builtin_parity(j & (int)sml);
                const float cr = sj ? p1r : p0r, ci = sj ? p1i : p0i;
                const float dr = sj ? q1r : q0r, di = sj ? q1i : q0i;
                const float Arr = ar[j], Aii = ai[j];
                ar[j] = cr * Arr - ci * Aii + dr * br[k] - di * bi[k];
                ai[j] = cr * Aii + ci * Arr + dr * bi[k] + di * br[k];
            }
        }
    } else {
        // mixed: partner is (lane ^ pmh, j ^ pml).
        // batch 4 pairs (16 shuffles) per chunk.
        constexpr int msb = 1 << (31 - __builtin_clz(pml));
#pragma unroll
        for (int c0 = 0; c0 < 32; c0 += 4) {
            float tAr[4], tAi[4], tBr[4], tBi[4];
#pragma unroll
            for (int k = 0; k < 4; ++k) {
                const int j  = pidx(c0 + k, msb);
                const int j2 = j ^ (int)pml;
                tAr[k] = __shfl_xor(ar[j2], (int)pmh, 64);
                tAi[k] = __shfl_xor(ai[j2], (int)pmh, 64);
                tBr[k] = __shfl_xor(ar[j],  (int)pmh, 64);
                tBi[k] = __shfl_xor(ai[j],  (int)pmh, 64);
            }
#pragma unroll
            for (int k = 0; k < 4; ++k) {
                const int j  = pidx(c0 + k, msb);
                const int j2 = j ^ (int)pml;
                const bool sj  = __builtin_parity(j & (int)sml);
                const bool sjB = flip ? !sj : sj;
                const float cAr = sj ? p1r : p0r, cAi = sj ? p1i : p0i;
                const float dAr = sj ? q1r : q0r, dAi = sj ? q1i : q0i;
                const float cBr = sjB ? p1r : p0r, cBi = sjB ? p1i : p0i;
                const float dBr = sjB ? q1r : q0r, dBi = sjB ? q1i : q0i;
                const float Arr = ar[j],  Aii = ai[j];
                const float Brr = ar[j2], Bii = ai[j2];
                ar[j]  = cAr * Arr - cAi * Aii + dAr * tAr[k] - dAi * tAi[k];
                ai[j]  = cAr * Aii + cAi * Arr + dAr * tAi[k] + dAi * tAr[k];
                ar[j2] = cBr * Brr - cBi * Bii + dBr * tBr[k] - dBi * tBi[k];
                ai[j2] = cBr * Bii + cBi * Brr + dBr * tBi[k] + dBi * tBr[k];
            }
        }
    }
}

template <int G>
__device__ __forceinline__ void apply_from(float (&ar)[64], float (&ai)[64],
                                           const float (*rotm)[8], int lane) {
    if constexpr (G < N_GATES) {
        apply_gate<G>(ar, ai, rotm[G], lane);
        apply_from<G + 1>(ar, ai, rotm, lane);
    }
}

__global__ __launch_bounds__(256, 2)
void qsim_kernel(const float* __restrict__ inputs,
                 const float* __restrict__ theta,
                 float* __restrict__ out, int B) {
    __shared__ float rotm[N_GATES][8];
    const int tid  = threadIdx.x;
    const int lane = tid & 63;
    int b = blockIdx.x * 4 + (tid >> 6);
    if (b >= B) b = B - 1;   // duplicate work, identical writes (B%4==0 normally)

    // ---- 48 shared Rot matrices (threads 0..47), PennyLane Rot(phi,th,om) ----
    if (tid < N_GATES) {
        const float* th = theta + tid * 3;   // tid = l*12 + w = gate index
        const float phi = th[0], tht = th[1], om = th[2];
        const float ct = __cosf(0.5f * tht), st = __sinf(0.5f * tht);
        const float a = 0.5f * (phi + om), d = 0.5f * (phi - om);
        const float ca = __cosf(a), sa = __sinf(a);
        const float cd = __cosf(d), sd = __sinf(d);
        rotm[tid][0] = ca * ct;  rotm[tid][1] = -sa * ct;   // u00 = e^{-ia} ct
        rotm[tid][2] = -cd * st; rotm[tid][3] = -sd * st;   // u01 = -e^{+id} st
        rotm[tid][4] = cd * st;  rotm[tid][5] = -sd * st;   // u10 = e^{-id} st
        rotm[tid][6] = ca * ct;  rotm[tid][7] = sa * ct;    // u11 = e^{+ia} ct
    }
    __syncthreads();

    // ---- init: RY-encoded product state (real) ----
    float cw[12], sw[12];
    const float* xin = inputs + b * 12;
#pragma unroll
    for (int w = 0; w < 12; ++w) {
        const float h = 0.5f * xin[w];
        cw[w] = __cosf(h);
        sw[w] = __sinf(h);
    }
    // lane bits: p bit (lb+6) <-> wire (5-lb)  =>  wire w (0..5) = lane bit (5-w)
    float prodL = 1.0f;
#pragma unroll
    for (int w = 0; w < 6; ++w)
        prodL *= ((lane >> (5 - w)) & 1) ? sw[w] : cw[w];

    float ar[64], ai[64];
    ar[0] = prodL;
#pragma unroll
    for (int k = 0; k < 6; ++k) {            // local bit k <-> wire (11-k)
        const int n = 1 << k;
#pragma unroll
        for (int idx = 0; idx < n; ++idx) {
            const float v = ar[idx];
            ar[idx + n] = v * sw[11 - k];
            ar[idx]     = v * cw[11 - k];
        }
    }
#pragma unroll
    for (int j = 0; j < 64; ++j) ai[j] = 0.0f;

    // ---- 4 layers x 12 Rot gates (CNOTs folded into masks) ----
    apply_from<0>(ar, ai, rotm, lane);

    // ---- measurement: <Z_q> = sum_p |amp|^2 * (1-2*parity(p & meas[q])) ----
    float sums[12];
#pragma unroll
    for (int q = 0; q < 12; ++q) sums[q] = 0.0f;
#pragma unroll
    for (int j = 0; j < 64; ++j) {
        const float p = ar[j] * ar[j] + ai[j] * ai[j];
#pragma unroll
        for (int q = 0; q < 12; ++q) {
            if (__builtin_parity(j & (int)(CIRC.meas[q] & 63u)))
                sums[q] -= p;
            else
                sums[q] += p;
        }
    }
#pragma unroll
    for (int q = 0; q < 12; ++q) {
        float v = (__popc(lane & (int)(CIRC.meas[q] >> 6)) & 1) ? -sums[q] : sums[q];
        v += __shfl_xor(v, 32, 64);
        v += __shfl_xor(v, 16, 64);
        v += __shfl_xor(v, 8, 64);
        v += __shfl_xor(v, 4, 64);
        v += __shfl_xor(v, 2, 64);
        v += __shfl_xor(v, 1, 64);
        if (lane == 0) out[b * 12 + q] = v;
    }
}

extern "C" void kernel_launch(void* const* d_in, const int* in_sizes, int n_in,
                              void* d_out, int out_size, void* d_ws, size_t ws_size,
                              hipStream_t stream) {
    const float* inputs = (const float*)d_in[0];
    const float* theta  = (const float*)d_in[1];
    float* out = (float*)d_out;
    const int B = in_sizes[0] / 12;
    const int blocks = (B + 3) / 4;
    qsim_kernel<<<blocks, 256, 0, stream>>>(inputs, theta, out, B);
}

// Round 5
// 382.153 us; speedup vs baseline: 1.9578x; 1.0654x over previous
//
#include <hip/hip_runtime.h>

// ---------------------------------------------------------------------------
// 12-qubit state-vector sim, one sample per 64-lane wave, 4 samples/block.
// Storage index p (12 bits): bits 0..5 = per-thread local index j,
// bits 6..11 = lane id. Logical index k = M*p over GF(2); CNOTs folded into
// M at compile time; each Rot gate = pair-mask (column of M^-1) + side-mask
// (row of M). Wire w <-> bit (11-w) of k (PennyLane big-endian).
// Invariant: parity(pair & side) == 1 (12-bit); partner's local side bit is
// sj ^ parity(pml & sml).
//
// Round-5 change: state stored as packed float2 (real,imag) and the complex
// gate update expressed as 4 packed FMAs (v_pk_fma_f32) per output instead
// of 8 scalar FMAs. Round-4 counters showed pure VALU-issue-bound (90% busy,
// ~2.6x the useful-FMA issue count, state partly in AGPRs): halving the
// arithmetic issue count is the lever.
// ---------------------------------------------------------------------------

#define N_GATES 48

typedef float v2f __attribute__((ext_vector_type(2)));

struct Circ {
    unsigned pair[N_GATES];
    unsigned side[N_GATES];
    unsigned meas[12];
};

constexpr Circ make_circ() {
    Circ c{};
    unsigned Mrow[12] = {}, Ucol[12] = {};   // M rows, M^-1 columns
    for (int i = 0; i < 12; ++i) { Mrow[i] = 1u << i; Ucol[i] = 1u << i; }
    int g = 0;
    for (int l = 0; l < 4; ++l) {
        for (int w = 0; w < 12; ++w) {
            int b = 11 - w;
            c.pair[g] = Ucol[b];
            c.side[g] = Mrow[b];
            ++g;
        }
        // CNOT chain: (0,1),(1,2),...,(10,11) then (11,0); bits c=11-i, t=10-i
        for (int i = 0; i < 11; ++i) {
            int cb = 11 - i, tb = 10 - i;
            Mrow[tb] ^= Mrow[cb];
            Ucol[cb] ^= Ucol[tb];
        }
        Mrow[11] ^= Mrow[0];   // CNOT(11 -> 0): control bit 0, target bit 11
        Ucol[0]  ^= Ucol[11];
    }
    for (int w = 0; w < 12; ++w) c.meas[w] = Mrow[11 - w];
    return c;
}

constexpr Circ CIRC = make_circ();

// c-th pair slot for in-thread/mixed gates: insert a 0 bit at position MSB
__device__ __forceinline__ constexpr int pidx(int c, int msb) {
    return ((c & ~(msb - 1)) << 1) | (c & (msb - 1));
}

// acc + coef * X (complex), packed: coefR = {cr,cr}, coefN = {-ci,ci}.
// result.x = acc.x + cr*X.x - ci*X.y ; result.y = acc.y + cr*X.y + ci*X.x
__device__ __forceinline__ v2f cmadd(v2f coefR, v2f coefN, v2f X, v2f acc) {
    acc = __builtin_elementwise_fma(coefR, X, acc);
    acc = __builtin_elementwise_fma(coefN, X.yx, acc);
    return acc;
}
// coef * X (complex), packed — first term of a chain (saves the zero init)
__device__ __forceinline__ v2f cmul(v2f coefR, v2f coefN, v2f X) {
    return __builtin_elementwise_fma(coefR, X, coefN * X.yx);
}

template <int G>
__device__ __forceinline__ void apply_gate(v2f (&st)[64],
                                           const float* __restrict__ m, int lane) {
    constexpr unsigned pm  = CIRC.pair[G];
    constexpr unsigned sm  = CIRC.side[G];
    constexpr unsigned pml = pm & 63u;
    constexpr unsigned pmh = pm >> 6;
    constexpr unsigned sml = sm & 63u;
    constexpr unsigned smh = sm >> 6;
    // partner's local side parity differs from ours iff this is 1
    constexpr bool flip = (__builtin_popcount(pml & sml) & 1) != 0;

    const float u00r = m[0], u00i = m[1], u01r = m[2], u01i = m[3];
    const float u10r = m[4], u10i = m[5], u11r = m[6], u11i = m[7];

    // runtime lane contribution to the side bit
    const int sL = __popc(lane & (int)smh) & 1;
    // own/partner coefficients for local-parity sj = 0 and sj = 1
    const float p0r = sL ? u11r : u00r, p0i = sL ? u11i : u00i;
    const float q0r = sL ? u10r : u01r, q0i = sL ? u10i : u01i;
    const float p1r = sL ? u00r : u11r, p1i = sL ? u00i : u11i;
    const float q1r = sL ? u01r : u10r, q1i = sL ? u01i : u10i;
    // packed coefficient vectors: R = {r,r}, N = {-i,i}
    const v2f P0R = {p0r, p0r}, P0N = {-p0i, p0i};
    const v2f Q0R = {q0r, q0r}, Q0N = {-q0i, q0i};
    const v2f P1R = {p1r, p1r}, P1N = {-p1i, p1i};
    const v2f Q1R = {q1r, q1r}, Q1N = {-q1i, q1i};

    if constexpr (pmh == 0u) {
        // purely in-thread pairs
        constexpr int msb = 1 << (31 - __builtin_clz(pml));
#pragma unroll
        for (int c = 0; c < 32; ++c) {
            const int j  = pidx(c, msb);
            const int j2 = j ^ (int)pml;
            const bool sj  = __builtin_parity(j & (int)sml);
            const bool sjB = flip ? !sj : sj;
            const v2f A = st[j], B = st[j2];
            st[j]  = cmadd(sj  ? P1R : P0R, sj  ? P1N : P0N, A,
                     cmul (sj  ? Q1R : Q0R, sj  ? Q1N : Q0N, B));
            st[j2] = cmadd(sjB ? P1R : P0R, sjB ? P1N : P0N, B,
                     cmul (sjB ? Q1R : Q0R, sjB ? Q1N : Q0N, A));
        }
    } else if constexpr (pml == 0u) {
        // pure cross-lane pairs: partner is same j in lane ^ pmh.
        // batch 8 elements (16 shuffles) per chunk for DS-pipe MLP.
#pragma unroll
        for (int j0 = 0; j0 < 64; j0 += 8) {
            v2f Bv[8];
#pragma unroll
            for (int k = 0; k < 8; ++k) {
                Bv[k].x = __shfl_xor(st[j0 + k].x, (int)pmh, 64);
                Bv[k].y = __shfl_xor(st[j0 + k].y, (int)pmh, 64);
            }
#pragma unroll
            for (int k = 0; k < 8; ++k) {
                const int j = j0 + k;
                const bool sj = __builtin_parity(j & (int)sml);
                st[j] = cmadd(sj ? P1R : P0R, sj ? P1N : P0N, st[j],
                        cmul (sj ? Q1R : Q0R, sj ? Q1N : Q0N, Bv[k]));
            }
        }
    } else {
        // mixed: partner is (lane ^ pmh, j ^ pml); batch 4 pairs (16 shuffles).
        constexpr int msb = 1 << (31 - __builtin_clz(pml));
#pragma unroll
        for (int c0 = 0; c0 < 32; c0 += 4) {
            v2f tA[4], tB[4];
#pragma unroll
            for (int k = 0; k < 4; ++k) {
                const int j  = pidx(c0 + k, msb);
                const int j2 = j ^ (int)pml;
                tA[k].x = __shfl_xor(st[j2].x, (int)pmh, 64);
                tA[k].y = __shfl_xor(st[j2].y, (int)pmh, 64);
                tB[k].x = __shfl_xor(st[j].x,  (int)pmh, 64);
                tB[k].y = __shfl_xor(st[j].y,  (int)pmh, 64);
            }
#pragma unroll
            for (int k = 0; k < 4; ++k) {
                const int j  = pidx(c0 + k, msb);
                const int j2 = j ^ (int)pml;
                const bool sj  = __builtin_parity(j & (int)sml);
                const bool sjB = flip ? !sj : sj;
                const v2f A = st[j], B = st[j2];
                st[j]  = cmadd(sj  ? P1R : P0R, sj  ? P1N : P0N, A,
                         cmul (sj  ? Q1R : Q0R, sj  ? Q1N : Q0N, tA[k]));
                st[j2] = cmadd(sjB ? P1R : P0R, sjB ? P1N : P0N, B,
                         cmul (sjB ? Q1R : Q0R, sjB ? Q1N : Q0N, tB[k]));
            }
        }
    }
}

template <int G>
__device__ __forceinline__ void apply_from(v2f (&st)[64],
                                           const float (*rotm)[8], int lane) {
    if constexpr (G < N_GATES) {
        apply_gate<G>(st, rotm[G], lane);
        apply_from<G + 1>(st, rotm, lane);
    }
}

__global__ __launch_bounds__(256, 2)
void qsim_kernel(const float* __restrict__ inputs,
                 const float* __restrict__ theta,
                 float* __restrict__ out, int B) {
    __shared__ float rotm[N_GATES][8];
    const int tid  = threadIdx.x;
    const int lane = tid & 63;
    int b = blockIdx.x * 4 + (tid >> 6);
    if (b >= B) b = B - 1;   // duplicate work, identical writes (B%4==0 normally)

    // ---- 48 shared Rot matrices (threads 0..47), PennyLane Rot(phi,th,om) ----
    if (tid < N_GATES) {
        const float* th = theta + tid * 3;   // tid = l*12 + w = gate index
        const float phi = th[0], tht = th[1], om = th[2];
        const float ct = __cosf(0.5f * tht), st = __sinf(0.5f * tht);
        const float a = 0.5f * (phi + om), d = 0.5f * (phi - om);
        const float ca = __cosf(a), sa = __sinf(a);
        const float cd = __cosf(d), sd = __sinf(d);
        rotm[tid][0] = ca * ct;  rotm[tid][1] = -sa * ct;   // u00 = e^{-ia} ct
        rotm[tid][2] = -cd * st; rotm[tid][3] = -sd * st;   // u01 = -e^{+id} st
        rotm[tid][4] = cd * st;  rotm[tid][5] = -sd * st;   // u10 = e^{-id} st
        rotm[tid][6] = ca * ct;  rotm[tid][7] = sa * ct;    // u11 = e^{+ia} ct
    }
    __syncthreads();

    // ---- init: RY-encoded product state (real) ----
    float cw[12], sw[12];
    const float* xin = inputs + b * 12;
#pragma unroll
    for (int w = 0; w < 12; ++w) {
        const float h = 0.5f * xin[w];
        cw[w] = __cosf(h);
        sw[w] = __sinf(h);
    }
    // lane bits: p bit (lb+6) <-> wire (5-lb)  =>  wire w (0..5) = lane bit (5-w)
    float prodL = 1.0f;
#pragma unroll
    for (int w = 0; w < 6; ++w)
        prodL *= ((lane >> (5 - w)) & 1) ? sw[w] : cw[w];

    float tmp[64];
    tmp[0] = prodL;
#pragma unroll
    for (int k = 0; k < 6; ++k) {            // local bit k <-> wire (11-k)
        const int n = 1 << k;
#pragma unroll
        for (int idx = 0; idx < n; ++idx) {
            const float v = tmp[idx];
            tmp[idx + n] = v * sw[11 - k];
            tmp[idx]     = v * cw[11 - k];
        }
    }
    v2f st[64];
#pragma unroll
    for (int j = 0; j < 64; ++j) st[j] = v2f{tmp[j], 0.0f};

    // ---- 4 layers x 12 Rot gates (CNOTs folded into masks) ----
    apply_from<0>(st, rotm, lane);

    // ---- measurement: <Z_q> = sum_p |amp|^2 * (1-2*parity(p & meas[q])) ----
    float sums[12];
#pragma unroll
    for (int q = 0; q < 12; ++q) sums[q] = 0.0f;
#pragma unroll
    for (int j = 0; j < 64; ++j) {
        const float p = st[j].x * st[j].x + st[j].y * st[j].y;
#pragma unroll
        for (int q = 0; q < 12; ++q) {
            if (__builtin_parity(j & (int)(CIRC.meas[q] & 63u)))
                sums[q] -= p;
            else
                sums[q] += p;
        }
    }
#pragma unroll
    for (int q = 0; q < 12; ++q) {
        float v = (__popc(lane & (int)(CIRC.meas[q] >> 6)) & 1) ? -sums[q] : sums[q];
        v += __shfl_xor(v, 32, 64);
        v += __shfl_xor(v, 16, 64);
        v += __shfl_xor(v, 8, 64);
        v += __shfl_xor(v, 4, 64);
        v += __shfl_xor(v, 2, 64);
        v += __shfl_xor(v, 1, 64);
        if (lane == 0) out[b * 12 + q] = v;
    }
}

extern "C" void kernel_launch(void* const* d_in, const int* in_sizes, int n_in,
                              void* d_out, int out_size, void* d_ws, size_t ws_size,
                              hipStream_t stream) {
    const float* inputs = (const float*)d_in[0];
    const float* theta  = (const float*)d_in[1];
    float* out = (float*)d_out;
    const int B = in_sizes[0] / 12;
    const int blocks = (B + 3) / 4;
    qsim_kernel<<<blocks, 256, 0, stream>>>(inputs, theta, out, B);
}